// Round 3
// baseline (394.229 us; speedup 1.0000x reference)
//
#include <hip/hip_runtime.h>
#include <math.h>

#define B_ 512
#define C_ 100
#define E_ 2048
#define F_ 128

typedef _Float16 f16x8 __attribute__((ext_vector_type(8)));
typedef _Float16 f16x4 __attribute__((ext_vector_type(4)));
typedef float    f32x4 __attribute__((ext_vector_type(4)));

// ---------------- kernel 0: x (fp32) -> xh (fp16)
__global__ __launch_bounds__(256)
void k_conv_x(const float* __restrict__ x, _Float16* __restrict__ xh) {
    const int row = blockIdx.x;          // 512 rows
    const int t   = threadIdx.x;         // 8 elems/thread
    const float* src = x + (size_t)row * E_ + t * 8;
    float4 a = *(const float4*)(src);
    float4 b = *(const float4*)(src + 4);
    f16x8 h;
    h[0] = (_Float16)a.x; h[1] = (_Float16)a.y; h[2] = (_Float16)a.z; h[3] = (_Float16)a.w;
    h[4] = (_Float16)b.x; h[5] = (_Float16)b.y; h[6] = (_Float16)b.z; h[7] = (_Float16)b.w;
    *(f16x8*)(xh + (size_t)row * E_ + t * 8) = h;
}

// ---------------- kernel 1: v_un[c,e] = sum_f W[c,f,e]*u[c,f];  nvsq[c] += sum_e v_un^2
// grid C_*8, block 128; each thread owns 2 consecutive e's (float2), 8-deep load batches.
__global__ __launch_bounds__(128)
void k_powiter_v(const float* __restrict__ W, const float* __restrict__ u,
                 float* __restrict__ v_un, float* __restrict__ nvsq) {
    int blk = blockIdx.x;
    int c   = blk >> 3;          // 8 e-chunks of 256 per class
    int ech = blk & 7;
    int e   = ech * 256 + threadIdx.x * 2;

    __shared__ float us[F_];
    us[threadIdx.x] = u[c * F_ + threadIdx.x];
    __syncthreads();

    const float* Wc = W + (size_t)c * F_ * E_ + e;
    float ax = 0.f, ay = 0.f;
    for (int f0 = 0; f0 < F_; f0 += 8) {
        float2 wv[8];
#pragma unroll
        for (int j = 0; j < 8; ++j) wv[j] = *(const float2*)(Wc + (size_t)(f0 + j) * E_);
        float4 u0 = *(const float4*)&us[f0];
        float4 u1 = *(const float4*)&us[f0 + 4];
        ax = fmaf(wv[0].x, u0.x, ax); ay = fmaf(wv[0].y, u0.x, ay);
        ax = fmaf(wv[1].x, u0.y, ax); ay = fmaf(wv[1].y, u0.y, ay);
        ax = fmaf(wv[2].x, u0.z, ax); ay = fmaf(wv[2].y, u0.z, ay);
        ax = fmaf(wv[3].x, u0.w, ax); ay = fmaf(wv[3].y, u0.w, ay);
        ax = fmaf(wv[4].x, u1.x, ax); ay = fmaf(wv[4].y, u1.x, ay);
        ax = fmaf(wv[5].x, u1.y, ax); ay = fmaf(wv[5].y, u1.y, ay);
        ax = fmaf(wv[6].x, u1.z, ax); ay = fmaf(wv[6].y, u1.z, ay);
        ax = fmaf(wv[7].x, u1.w, ax); ay = fmaf(wv[7].y, u1.w, ay);
    }
    *(float2*)(v_un + (size_t)c * E_ + e) = make_float2(ax, ay);

    float s = ax * ax + ay * ay;
    for (int off = 32; off; off >>= 1) s += __shfl_down(s, off, 64);
    __shared__ float wsum[2];
    int lane = threadIdx.x & 63, w = threadIdx.x >> 6;
    if (lane == 0) wsum[w] = s;
    __syncthreads();
    if (threadIdx.x == 0) atomicAdd(&nvsq[c], wsum[0] + wsum[1]);
}

// ---------------- kernel 2: tsq[c] += sum_f (W v_un)_f^2 ; also W -> Wh (fp16)
// One wave per f-row; all 16 loads batched into registers for full MLP.
__global__ __launch_bounds__(256)
void k_powiter_t(const float* __restrict__ W, const float* __restrict__ v_un,
                 float* __restrict__ tsq, _Float16* __restrict__ Wh) {
    int blk = blockIdx.x;
    int c  = blk >> 5;           // 32 f-groups of 4 per class
    int fg = blk & 31;
    int wv = threadIdx.x >> 6, lane = threadIdx.x & 63;
    int f  = fg * 4 + wv;        // one wave per f-row

    const float* Wr  = W    + ((size_t)c * F_ + f) * E_;
    const float* vr  = v_un + (size_t)c * E_;
    _Float16*    Whr = Wh   + ((size_t)c * F_ + f) * E_;

    float4 w4[8], v4[8];
#pragma unroll
    for (int g = 0; g < 8; ++g) w4[g] = *(const float4*)(Wr + g * 256 + lane * 4);
#pragma unroll
    for (int g = 0; g < 8; ++g) v4[g] = *(const float4*)(vr + g * 256 + lane * 4);

    float s = 0.f;
#pragma unroll
    for (int g = 0; g < 8; ++g) {
        s = fmaf(w4[g].x, v4[g].x, s); s = fmaf(w4[g].y, v4[g].y, s);
        s = fmaf(w4[g].z, v4[g].z, s); s = fmaf(w4[g].w, v4[g].w, s);
        f16x4 h;
        h[0] = (_Float16)w4[g].x; h[1] = (_Float16)w4[g].y;
        h[2] = (_Float16)w4[g].z; h[3] = (_Float16)w4[g].w;
        *(f16x4*)(Whr + g * 256 + lane * 4) = h;
    }
    for (int off = 32; off; off >>= 1) s += __shfl_down(s, off, 64);
    if (lane == 0) atomicAdd(&tsq[c], s * s);
}

// ---------------- kernel 3: fused MFMA GEMM + dist2 + exp
// grid (4 b-tiles, 100 classes), block 256 = 4 waves (2x2).
// Tile M=128, N=128 (all f), BK=64. Wave owns 64x64: 4x4 tiles of 16x16,
// mfma_f32_16x16x32_f16, two 32-k subchunks. Register prefetch of next tile.
#define BKM 64
#define LDP 72   // 64 + 8 halves pad; 144 B row stride (2-way bank alias = free)

__global__ __launch_bounds__(256)
void k_main(const _Float16* __restrict__ xh, const _Float16* __restrict__ Wh,
            const float* __restrict__ bias, const float* __restrict__ cent,
            const float* __restrict__ nvsq, const float* __restrict__ tsq,
            float* __restrict__ out) {
    const int c  = blockIdx.y;
    const int b0 = blockIdx.x * 128;
    const int t  = threadIdx.x;
    const int w  = t >> 6;
    const int l  = t & 63;
    const int wm = w & 1, wn = w >> 1;
    const int ln = l & 15, quad = l >> 4;

    __shared__ _Float16 XsT[128][LDP];
    __shared__ _Float16 WsT[128][LDP];

    f32x4 acc[4][4];
#pragma unroll
    for (int mt = 0; mt < 4; ++mt)
#pragma unroll
        for (int nt = 0; nt < 4; ++nt) acc[mt][nt] = (f32x4){0.f, 0.f, 0.f, 0.f};

    // staging: 128 rows x 64 halves per tile, 2 threads/row, 32 halves (64 B) each
    const int srow = t >> 1, scol = (t & 1) * 32;
    const _Float16* xsrc = xh + (size_t)(b0 + srow) * E_ + scol;
    const _Float16* wsrc = Wh + ((size_t)c * F_ + srow) * E_ + scol;

    uint4 xa[2], xb[2], wa[2], wb[2];
    // prologue: load tile 0
    xa[0] = *(const uint4*)(xsrc);      xa[1] = *(const uint4*)(xsrc + 8);
    xb[0] = *(const uint4*)(xsrc + 16); xb[1] = *(const uint4*)(xsrc + 24);
    wa[0] = *(const uint4*)(wsrc);      wa[1] = *(const uint4*)(wsrc + 8);
    wb[0] = *(const uint4*)(wsrc + 16); wb[1] = *(const uint4*)(wsrc + 24);

    for (int k0 = 0; k0 < E_; k0 += BKM) {
        *(uint4*)&XsT[srow][scol]      = xa[0];
        *(uint4*)&XsT[srow][scol + 8]  = xa[1];
        *(uint4*)&XsT[srow][scol + 16] = xb[0];
        *(uint4*)&XsT[srow][scol + 24] = xb[1];
        *(uint4*)&WsT[srow][scol]      = wa[0];
        *(uint4*)&WsT[srow][scol + 8]  = wa[1];
        *(uint4*)&WsT[srow][scol + 16] = wb[0];
        *(uint4*)&WsT[srow][scol + 24] = wb[1];
        __syncthreads();

        // prefetch next tile into registers (overlaps with MFMA below)
        if (k0 + BKM < E_) {
            const _Float16* xs = xsrc + k0 + BKM;
            const _Float16* ws = wsrc + k0 + BKM;
            xa[0] = *(const uint4*)(xs);      xa[1] = *(const uint4*)(xs + 8);
            xb[0] = *(const uint4*)(xs + 16); xb[1] = *(const uint4*)(xs + 24);
            wa[0] = *(const uint4*)(ws);      wa[1] = *(const uint4*)(ws + 8);
            wb[0] = *(const uint4*)(ws + 16); wb[1] = *(const uint4*)(ws + 24);
        }

#pragma unroll
        for (int kk = 0; kk < BKM; kk += 32) {
            f16x8 av[4], bv[4];
#pragma unroll
            for (int mt = 0; mt < 4; ++mt)
                av[mt] = *(const f16x8*)&XsT[wm * 64 + mt * 16 + ln][kk + quad * 8];
#pragma unroll
            for (int nt = 0; nt < 4; ++nt)
                bv[nt] = *(const f16x8*)&WsT[wn * 64 + nt * 16 + ln][kk + quad * 8];
#pragma unroll
            for (int mt = 0; mt < 4; ++mt)
#pragma unroll
                for (int nt = 0; nt < 4; ++nt)
                    acc[mt][nt] = __builtin_amdgcn_mfma_f32_16x16x32_f16(
                        av[mt], bv[nt], acc[mt][nt], 0, 0, 0);
        }
        __syncthreads();
    }

    const float rsigma = sqrtf(nvsq[c] / tsq[c]);

    // epilogue: z = acc*rsigma + bias; partial dist2 over this lane's 4 f's
    // C/D layout: col (f) = ln, row (m) = quad*4 + reg
    float bi[4], ce[4];
#pragma unroll
    for (int nt = 0; nt < 4; ++nt) {
        int fidx = wn * 64 + nt * 16 + ln;
        bi[nt] = bias[c * F_ + fidx];
        ce[nt] = cent[c * F_ + fidx];
    }

    float* red = (float*)&XsT[0][0];   // red[128][2] floats, reused LDS

#pragma unroll
    for (int mt = 0; mt < 4; ++mt) {
#pragma unroll
        for (int r = 0; r < 4; ++r) {
            float part = 0.f;
#pragma unroll
            for (int nt = 0; nt < 4; ++nt) {
                float z = fmaf(acc[mt][nt][r], rsigma, bi[nt]);
                float d = ce[nt] - z;
                part = fmaf(d, d, part);
            }
            part += __shfl_xor(part, 1, 64);
            part += __shfl_xor(part, 2, 64);
            part += __shfl_xor(part, 4, 64);
            part += __shfl_xor(part, 8, 64);
            if (ln == 0) {
                int m = wm * 64 + mt * 16 + quad * 4 + r;
                red[m * 2 + wn] = part;
            }
        }
    }
    __syncthreads();
    if (t < 128) {
        float d2 = red[t * 2] + red[t * 2 + 1];
        out[(size_t)(b0 + t) * C_ + c] = expf(-0.5f * d2);
    }
}

extern "C" void kernel_launch(void* const* d_in, const int* in_sizes, int n_in,
                              void* d_out, int out_size, void* d_ws, size_t ws_size,
                              hipStream_t stream) {
    const float* x  = (const float*)d_in[0];
    const float* W  = (const float*)d_in[1];
    const float* b  = (const float*)d_in[2];
    const float* u  = (const float*)d_in[3];
    const float* cc = (const float*)d_in[4];
    float* out = (float*)d_out;

    // workspace layout (all 16B aligned)
    char* ws = (char*)d_ws;
    _Float16* Wh   = (_Float16*)ws;                               // C*F*E halves = 52,428,800 B
    _Float16* xh   = (_Float16*)(ws + (size_t)C_ * F_ * E_ * 2);  // B*E halves   =  2,097,152 B
    float*    v_un = (float*)(ws + (size_t)C_ * F_ * E_ * 2 + (size_t)B_ * E_ * 2); // C*E floats
    float*    nvsq = v_un + (size_t)C_ * E_;
    float*    tsq  = nvsq + C_;

    hipMemsetAsync(nvsq, 0, 2 * C_ * sizeof(float), stream);

    k_conv_x<<<B_, 256, 0, stream>>>(x, xh);
    k_powiter_v<<<C_ * 8, 128, 0, stream>>>(W, u, v_un, nvsq);
    k_powiter_t<<<C_ * 32, 256, 0, stream>>>(W, v_un, tsq, Wh);

    dim3 grid(B_ / 128, C_);
    k_main<<<grid, 256, 0, stream>>>(xh, Wh, b, cc, nvsq, tsq, out);
}

// Round 4
// 298.269 us; speedup vs baseline: 1.3217x; 1.3217x over previous
//
#include <hip/hip_runtime.h>
#include <math.h>

#define B_ 512
#define C_ 100
#define E_ 2048
#define F_ 128

typedef _Float16 f16x8 __attribute__((ext_vector_type(8)));
typedef _Float16 f16x4 __attribute__((ext_vector_type(4)));
typedef float    f32x4 __attribute__((ext_vector_type(4)));

#define AS1q __attribute__((address_space(1)))
#define AS3q __attribute__((address_space(3)))

// async global->LDS DMA, 16 B per lane; LDS dest = wave-uniform base + lane*16
__device__ __forceinline__ void gl_lds16(const void* g, void* lds_base) {
    __builtin_amdgcn_global_load_lds((const AS1q void*)g, (AS3q void*)lds_base, 16, 0, 0);
}

// ---------------- kernel 0: x (fp32) -> xh (fp16)
__global__ __launch_bounds__(256)
void k_conv_x(const float* __restrict__ x, _Float16* __restrict__ xh) {
    const int row = blockIdx.x;          // 512 rows
    const int t   = threadIdx.x;         // 8 elems/thread
    const float* src = x + (size_t)row * E_ + t * 8;
    float4 a = *(const float4*)(src);
    float4 b = *(const float4*)(src + 4);
    f16x8 h;
    h[0] = (_Float16)a.x; h[1] = (_Float16)a.y; h[2] = (_Float16)a.z; h[3] = (_Float16)a.w;
    h[4] = (_Float16)b.x; h[5] = (_Float16)b.y; h[6] = (_Float16)b.z; h[7] = (_Float16)b.w;
    *(f16x8*)(xh + (size_t)row * E_ + t * 8) = h;
}

// ---------------- kernel 1: v_un[c,e] = sum_f W[c,f,e]*u[c,f];  nvsq[c] += sum_e v_un^2
__global__ __launch_bounds__(128)
void k_powiter_v(const float* __restrict__ W, const float* __restrict__ u,
                 float* __restrict__ v_un, float* __restrict__ nvsq) {
    int blk = blockIdx.x;
    int c   = blk >> 3;          // 8 e-chunks of 256 per class
    int ech = blk & 7;
    int e   = ech * 256 + threadIdx.x * 2;

    __shared__ float us[F_];
    us[threadIdx.x] = u[c * F_ + threadIdx.x];
    __syncthreads();

    const float* Wc = W + (size_t)c * F_ * E_ + e;
    float ax = 0.f, ay = 0.f;
    for (int f0 = 0; f0 < F_; f0 += 8) {
        float2 wv[8];
#pragma unroll
        for (int j = 0; j < 8; ++j) wv[j] = *(const float2*)(Wc + (size_t)(f0 + j) * E_);
        float4 u0 = *(const float4*)&us[f0];
        float4 u1 = *(const float4*)&us[f0 + 4];
        ax = fmaf(wv[0].x, u0.x, ax); ay = fmaf(wv[0].y, u0.x, ay);
        ax = fmaf(wv[1].x, u0.y, ax); ay = fmaf(wv[1].y, u0.y, ay);
        ax = fmaf(wv[2].x, u0.z, ax); ay = fmaf(wv[2].y, u0.z, ay);
        ax = fmaf(wv[3].x, u0.w, ax); ay = fmaf(wv[3].y, u0.w, ay);
        ax = fmaf(wv[4].x, u1.x, ax); ay = fmaf(wv[4].y, u1.x, ay);
        ax = fmaf(wv[5].x, u1.y, ax); ay = fmaf(wv[5].y, u1.y, ay);
        ax = fmaf(wv[6].x, u1.z, ax); ay = fmaf(wv[6].y, u1.z, ay);
        ax = fmaf(wv[7].x, u1.w, ax); ay = fmaf(wv[7].y, u1.w, ay);
    }
    *(float2*)(v_un + (size_t)c * E_ + e) = make_float2(ax, ay);

    float s = ax * ax + ay * ay;
    for (int off = 32; off; off >>= 1) s += __shfl_down(s, off, 64);
    __shared__ float wsum[2];
    int lane = threadIdx.x & 63, w = threadIdx.x >> 6;
    if (lane == 0) wsum[w] = s;
    __syncthreads();
    if (threadIdx.x == 0) atomicAdd(&nvsq[c], wsum[0] + wsum[1]);
}

// ---------------- kernel 2: tsq[c] += sum_f (W v_un)_f^2 ; also W -> Wh (fp16)
__global__ __launch_bounds__(256)
void k_powiter_t(const float* __restrict__ W, const float* __restrict__ v_un,
                 float* __restrict__ tsq, _Float16* __restrict__ Wh) {
    int blk = blockIdx.x;
    int c  = blk >> 5;           // 32 f-groups of 4 per class
    int fg = blk & 31;
    int wv = threadIdx.x >> 6, lane = threadIdx.x & 63;
    int f  = fg * 4 + wv;        // one wave per f-row

    const float* Wr  = W    + ((size_t)c * F_ + f) * E_;
    const float* vr  = v_un + (size_t)c * E_;
    _Float16*    Whr = Wh   + ((size_t)c * F_ + f) * E_;

    float4 w4[8], v4[8];
#pragma unroll
    for (int g = 0; g < 8; ++g) w4[g] = *(const float4*)(Wr + g * 256 + lane * 4);
#pragma unroll
    for (int g = 0; g < 8; ++g) v4[g] = *(const float4*)(vr + g * 256 + lane * 4);

    float s = 0.f;
#pragma unroll
    for (int g = 0; g < 8; ++g) {
        s = fmaf(w4[g].x, v4[g].x, s); s = fmaf(w4[g].y, v4[g].y, s);
        s = fmaf(w4[g].z, v4[g].z, s); s = fmaf(w4[g].w, v4[g].w, s);
        f16x4 h;
        h[0] = (_Float16)w4[g].x; h[1] = (_Float16)w4[g].y;
        h[2] = (_Float16)w4[g].z; h[3] = (_Float16)w4[g].w;
        *(f16x4*)(Whr + g * 256 + lane * 4) = h;
    }
    for (int off = 32; off; off >>= 1) s += __shfl_down(s, off, 64);
    if (lane == 0) atomicAdd(&tsq[c], s * s);
}

// ---------------- kernel 3: fused MFMA GEMM + dist2 + exp
// grid (4 b-tiles, 100 classes), block 128 = 2 waves.
// Tile M=128, N=128, BK=64. Wave w owns rows [w*64, w*64+64) x all 128 f:
// 4 mt x 8 nt tiles of 16x16, mfma_f32_16x16x32_f16.
// Staging: global_load_lds (16 B/lane), unpadded LDS rows (64 halves = 128 B)
// with XOR chunk swizzle: logical 16B-chunk g of row r stored at slot g^(r&7).
// The swizzle is applied on the DMA *source* address (lane i of instr id
// covers row id*8+i/8, LDS slot i%8  ->  source chunk (i%8)^(i/8)).
__global__ __launch_bounds__(128, 2)
void k_main(const _Float16* __restrict__ xh, const _Float16* __restrict__ Wh,
            const float* __restrict__ bias, const float* __restrict__ cent,
            const float* __restrict__ nvsq, const float* __restrict__ tsq,
            float* __restrict__ out) {
    const int c  = blockIdx.y;
    const int b0 = blockIdx.x * 128;
    const int t  = threadIdx.x;      // 0..127
    const int w  = t >> 6;           // 0..1
    const int l  = t & 63;
    const int ln = l & 15, quad = l >> 4;

    __shared__ _Float16 Xs[128 * 64];   // 16 KB
    __shared__ _Float16 Ws[128 * 64];   // 16 KB

    f32x4 acc[4][8];
#pragma unroll
    for (int mt = 0; mt < 4; ++mt)
#pragma unroll
        for (int nt = 0; nt < 8; ++nt) acc[mt][nt] = (f32x4){0.f, 0.f, 0.f, 0.f};

    // DMA source base for this lane (swizzled chunk, loop-invariant part)
    const int lr = l >> 3;               // sub-row within an 8-row DMA instr
    const int lg = (l & 7) ^ lr;         // swizzled source chunk index
    const _Float16* xsrc = xh + (size_t)(b0 + w * 64 + lr) * E_ + lg * 8;
    const _Float16* wsrc = Wh + ((size_t)c * F_ + w * 64 + lr) * E_ + lg * 8;

    for (int k0 = 0; k0 < E_; k0 += 64) {
        // stage X rows [w*64, w*64+64), 8 rows (1 KB) per DMA instr
#pragma unroll
        for (int q = 0; q < 8; ++q)
            gl_lds16(xsrc + (size_t)q * 8 * E_ + k0, &Xs[(w * 8 + q) * 512]);
#pragma unroll
        for (int q = 0; q < 8; ++q)
            gl_lds16(wsrc + (size_t)q * 8 * E_ + k0, &Ws[(w * 8 + q) * 512]);
        __syncthreads();

#pragma unroll
        for (int kk = 0; kk < 64; kk += 32) {
            const int g0 = (kk >> 3) + quad;          // logical chunk
            const int sw = (g0 ^ (ln & 7)) * 8;       // swizzled half-offset in row
            f16x8 av[4], bv[8];
#pragma unroll
            for (int mt = 0; mt < 4; ++mt) {
                int r = w * 64 + mt * 16 + ln;
                av[mt] = *(const f16x8*)&Xs[r * 64 + sw];
            }
#pragma unroll
            for (int nt = 0; nt < 8; ++nt) {
                int r = nt * 16 + ln;
                bv[nt] = *(const f16x8*)&Ws[r * 64 + sw];
            }
#pragma unroll
            for (int mt = 0; mt < 4; ++mt)
#pragma unroll
                for (int nt = 0; nt < 8; ++nt)
                    acc[mt][nt] = __builtin_amdgcn_mfma_f32_16x16x32_f16(
                        av[mt], bv[nt], acc[mt][nt], 0, 0, 0);
        }
        __syncthreads();
    }

    const float rsigma = sqrtf(nvsq[c] / tsq[c]);

    // epilogue, all in-wave: lane's 8 f's are nt*16+ln; rows = quad*4+reg
    float bi[8], ce[8];
#pragma unroll
    for (int nt = 0; nt < 8; ++nt) {
        int f = nt * 16 + ln;
        bi[nt] = bias[c * F_ + f];
        ce[nt] = cent[c * F_ + f];
    }

#pragma unroll
    for (int mt = 0; mt < 4; ++mt) {
#pragma unroll
        for (int r = 0; r < 4; ++r) {
            float part = 0.f;
#pragma unroll
            for (int nt = 0; nt < 8; ++nt) {
                float z = fmaf(acc[mt][nt][r], rsigma, bi[nt]);
                float d = ce[nt] - z;
                part = fmaf(d, d, part);
            }
            part += __shfl_xor(part, 1, 64);
            part += __shfl_xor(part, 2, 64);
            part += __shfl_xor(part, 4, 64);
            part += __shfl_xor(part, 8, 64);
            if (ln == 0) {
                int m = w * 64 + mt * 16 + quad * 4 + r;
                out[(size_t)(b0 + m) * C_ + c] = expf(-0.5f * part);
            }
        }
    }
}

extern "C" void kernel_launch(void* const* d_in, const int* in_sizes, int n_in,
                              void* d_out, int out_size, void* d_ws, size_t ws_size,
                              hipStream_t stream) {
    const float* x  = (const float*)d_in[0];
    const float* W  = (const float*)d_in[1];
    const float* b  = (const float*)d_in[2];
    const float* u  = (const float*)d_in[3];
    const float* cc = (const float*)d_in[4];
    float* out = (float*)d_out;

    // workspace layout (all 16B aligned)
    char* ws = (char*)d_ws;
    _Float16* Wh   = (_Float16*)ws;                               // C*F*E halves = 52,428,800 B
    _Float16* xh   = (_Float16*)(ws + (size_t)C_ * F_ * E_ * 2);  // B*E halves   =  2,097,152 B
    float*    v_un = (float*)(ws + (size_t)C_ * F_ * E_ * 2 + (size_t)B_ * E_ * 2); // C*E floats
    float*    nvsq = v_un + (size_t)C_ * E_;
    float*    tsq  = nvsq + C_;

    hipMemsetAsync(nvsq, 0, 2 * C_ * sizeof(float), stream);

    k_conv_x<<<B_, 256, 0, stream>>>(x, xh);
    k_powiter_v<<<C_ * 8, 128, 0, stream>>>(W, u, v_un, nvsq);
    k_powiter_t<<<C_ * 32, 256, 0, stream>>>(W, v_un, tsq, Wh);

    dim3 grid(B_ / 128, C_);
    k_main<<<grid, 128, 0, stream>>>(xh, Wh, b, cc, nvsq, tsq, out);
}

// Round 5
// 255.921 us; speedup vs baseline: 1.5404x; 1.1655x over previous
//
#include <hip/hip_runtime.h>
#include <math.h>

#define B_ 512
#define C_ 100
#define E_ 2048
#define F_ 128

typedef _Float16 f16x8 __attribute__((ext_vector_type(8)));
typedef _Float16 f16x4 __attribute__((ext_vector_type(4)));
typedef float    f32x4 __attribute__((ext_vector_type(4)));

#define AS1q __attribute__((address_space(1)))
#define AS3q __attribute__((address_space(3)))

// async global->LDS DMA, 16 B per lane; LDS dest = wave-uniform base + lane*16
__device__ __forceinline__ void gl_lds16(const void* g, void* lds_base) {
    __builtin_amdgcn_global_load_lds((const AS1q void*)g, (AS3q void*)lds_base, 16, 0, 0);
}

// ---------------- kernel 0a: x (fp32) -> xh (fp16).  512 blocks x 256 thr
__global__ __launch_bounds__(256)
void k_conv_x(const float* __restrict__ x, _Float16* __restrict__ xh) {
    const int row = blockIdx.x;
    const int t   = threadIdx.x;
    const float* src = x + (size_t)row * E_ + t * 8;
    float4 a = *(const float4*)(src);
    float4 b = *(const float4*)(src + 4);
    f16x8 h;
    h[0] = (_Float16)a.x; h[1] = (_Float16)a.y; h[2] = (_Float16)a.z; h[3] = (_Float16)a.w;
    h[4] = (_Float16)b.x; h[5] = (_Float16)b.y; h[6] = (_Float16)b.z; h[7] = (_Float16)b.w;
    *(f16x8*)(xh + (size_t)row * E_ + t * 8) = h;
}

// ---------------- kernel 0b: W (fp32) -> Wh (fp16), pure streaming.
// 800 blocks x 256 thr, 16 iters x 8 floats/thread = 32768 floats/block.
__global__ __launch_bounds__(256)
void k_conv_w(const float* __restrict__ W, _Float16* __restrict__ Wh) {
    const size_t base = (size_t)blockIdx.x * 32768 + threadIdx.x * 8;
#pragma unroll
    for (int it = 0; it < 16; ++it) {
        const size_t idx = base + (size_t)it * 2048;
        float4 a = *(const float4*)(W + idx);
        float4 b = *(const float4*)(W + idx + 4);
        f16x8 h;
        h[0] = (_Float16)a.x; h[1] = (_Float16)a.y; h[2] = (_Float16)a.z; h[3] = (_Float16)a.w;
        h[4] = (_Float16)b.x; h[5] = (_Float16)b.y; h[6] = (_Float16)b.z; h[7] = (_Float16)b.w;
        *(f16x8*)(Wh + idx) = h;
    }
}

// ---------------- kernel 1: per-class G = Wh Wh^T (in registers) -> rsig[c]
// rsig = sqrt(u^T G u) / ||G u||.  grid C_, block 256 = 4 waves (2x2).
// Single 128x64 LDS tile staged via global_load_lds + XOR chunk swizzle;
// A and B fragments both read from it (B-row-as-fragment => Wh Wh^T).
__global__ __launch_bounds__(256, 1)
void k_gramsig(const _Float16* __restrict__ Wh, const float* __restrict__ u,
               float* __restrict__ rsig) {
    const int c  = blockIdx.x;
    const int t  = threadIdx.x;
    const int w  = t >> 6;
    const int l  = t & 63;
    const int wm = w & 1, wn = w >> 1;
    const int ln = l & 15, quad = l >> 4;

    __shared__ _Float16 Ts[128 * 64];   // 16 KB

    f32x4 acc[4][4];
#pragma unroll
    for (int mt = 0; mt < 4; ++mt)
#pragma unroll
        for (int nt = 0; nt < 4; ++nt) acc[mt][nt] = (f32x4){0.f, 0.f, 0.f, 0.f};

    // DMA: wave w stages rows [w*32, w*32+32), 4 instrs x 8 rows (1 KB each)
    const int lr = l >> 3;               // sub-row within an 8-row DMA instr
    const int lg = (l & 7) ^ lr;         // swizzled source chunk
    const _Float16* wsrc = Wh + ((size_t)c * F_ + w * 32 + lr) * E_ + lg * 8;

    for (int k0 = 0; k0 < E_; k0 += 64) {
#pragma unroll
        for (int q = 0; q < 4; ++q)
            gl_lds16(wsrc + (size_t)q * 8 * E_ + k0, &Ts[(w * 4 + q) * 512]);
        __syncthreads();

#pragma unroll
        for (int kk = 0; kk < 64; kk += 32) {
            const int g0 = (kk >> 3) + quad;
            const int sw = (g0 ^ (ln & 7)) * 8;
            f16x8 av[4], bv[4];
#pragma unroll
            for (int mt = 0; mt < 4; ++mt)
                av[mt] = *(const f16x8*)&Ts[(wm * 64 + mt * 16 + ln) * 64 + sw];
#pragma unroll
            for (int nt = 0; nt < 4; ++nt)
                bv[nt] = *(const f16x8*)&Ts[(wn * 64 + nt * 16 + ln) * 64 + sw];
#pragma unroll
            for (int mt = 0; mt < 4; ++mt)
#pragma unroll
                for (int nt = 0; nt < 4; ++nt)
                    acc[mt][nt] = __builtin_amdgcn_mfma_f32_16x16x32_f16(
                        av[mt], bv[nt], acc[mt][nt], 0, 0, 0);
        }
        __syncthreads();
    }

    // ---- epilogue: y = G u ; rsig = sqrt(u.y / y.y)
    // lane holds G[m][n]: m = wm*64+mt*16+quad*4+r, n = wn*64+nt*16+ln
    const float* uc = u + (size_t)c * F_;
    float un[4];
#pragma unroll
    for (int nt = 0; nt < 4; ++nt) un[nt] = uc[wn * 64 + nt * 16 + ln];

    float* ypart = (float*)&Ts[0];      // [128][2] floats, reuse LDS

#pragma unroll
    for (int mt = 0; mt < 4; ++mt) {
#pragma unroll
        for (int r = 0; r < 4; ++r) {
            float py = acc[mt][0][r] * un[0];
            py = fmaf(acc[mt][1][r], un[1], py);
            py = fmaf(acc[mt][2][r], un[2], py);
            py = fmaf(acc[mt][3][r], un[3], py);
            py += __shfl_xor(py, 1, 64);
            py += __shfl_xor(py, 2, 64);
            py += __shfl_xor(py, 4, 64);
            py += __shfl_xor(py, 8, 64);
            if (ln == 0) {
                int m = wm * 64 + mt * 16 + quad * 4 + r;
                ypart[m * 2 + wn] = py;
            }
        }
    }
    __syncthreads();

    __shared__ float red2[2][2];
    if (t < 128) {
        float y   = ypart[t * 2] + ypart[t * 2 + 1];
        float nvp = uc[t] * y;
        float tsp = y * y;
        for (int off = 32; off; off >>= 1) {
            nvp += __shfl_down(nvp, off, 64);
            tsp += __shfl_down(tsp, off, 64);
        }
        if (l == 0) { red2[t >> 6][0] = nvp; red2[t >> 6][1] = tsp; }
    }
    __syncthreads();
    if (t == 0) {
        float nv = red2[0][0] + red2[1][0];
        float ts = red2[0][1] + red2[1][1];
        rsig[c] = sqrtf(nv / ts);
    }
}

// ---------------- kernel 2: fused MFMA GEMM + dist2 + exp  (round-4 structure)
// grid (4 b-tiles, 100 classes), block 128 = 2 waves; M=128, N=128, BK=64.
__global__ __launch_bounds__(128, 2)
void k_main(const _Float16* __restrict__ xh, const _Float16* __restrict__ Wh,
            const float* __restrict__ bias, const float* __restrict__ cent,
            const float* __restrict__ rsig, float* __restrict__ out) {
    const int c  = blockIdx.y;
    const int b0 = blockIdx.x * 128;
    const int t  = threadIdx.x;      // 0..127
    const int w  = t >> 6;           // 0..1
    const int l  = t & 63;
    const int ln = l & 15, quad = l >> 4;

    __shared__ _Float16 Xs[128 * 64];   // 16 KB
    __shared__ _Float16 Ws[128 * 64];   // 16 KB

    f32x4 acc[4][8];
#pragma unroll
    for (int mt = 0; mt < 4; ++mt)
#pragma unroll
        for (int nt = 0; nt < 8; ++nt) acc[mt][nt] = (f32x4){0.f, 0.f, 0.f, 0.f};

    const int lr = l >> 3;
    const int lg = (l & 7) ^ lr;
    const _Float16* xsrc = xh + (size_t)(b0 + w * 64 + lr) * E_ + lg * 8;
    const _Float16* wsrc = Wh + ((size_t)c * F_ + w * 64 + lr) * E_ + lg * 8;

    for (int k0 = 0; k0 < E_; k0 += 64) {
#pragma unroll
        for (int q = 0; q < 8; ++q)
            gl_lds16(xsrc + (size_t)q * 8 * E_ + k0, &Xs[(w * 8 + q) * 512]);
#pragma unroll
        for (int q = 0; q < 8; ++q)
            gl_lds16(wsrc + (size_t)q * 8 * E_ + k0, &Ws[(w * 8 + q) * 512]);
        __syncthreads();

#pragma unroll
        for (int kk = 0; kk < 64; kk += 32) {
            const int g0 = (kk >> 3) + quad;
            const int sw = (g0 ^ (ln & 7)) * 8;
            f16x8 av[4], bv[8];
#pragma unroll
            for (int mt = 0; mt < 4; ++mt)
                av[mt] = *(const f16x8*)&Xs[(w * 64 + mt * 16 + ln) * 64 + sw];
#pragma unroll
            for (int nt = 0; nt < 8; ++nt)
                bv[nt] = *(const f16x8*)&Ws[(nt * 16 + ln) * 64 + sw];
#pragma unroll
            for (int mt = 0; mt < 4; ++mt)
#pragma unroll
                for (int nt = 0; nt < 8; ++nt)
                    acc[mt][nt] = __builtin_amdgcn_mfma_f32_16x16x32_f16(
                        av[mt], bv[nt], acc[mt][nt], 0, 0, 0);
        }
        __syncthreads();
    }

    const float rsigma = rsig[c];

    float bi[8], ce[8];
#pragma unroll
    for (int nt = 0; nt < 8; ++nt) {
        int f = nt * 16 + ln;
        bi[nt] = bias[c * F_ + f];
        ce[nt] = cent[c * F_ + f];
    }

#pragma unroll
    for (int mt = 0; mt < 4; ++mt) {
#pragma unroll
        for (int r = 0; r < 4; ++r) {
            float part = 0.f;
#pragma unroll
            for (int nt = 0; nt < 8; ++nt) {
                float z = fmaf(acc[mt][nt][r], rsigma, bi[nt]);
                float d = ce[nt] - z;
                part = fmaf(d, d, part);
            }
            part += __shfl_xor(part, 1, 64);
            part += __shfl_xor(part, 2, 64);
            part += __shfl_xor(part, 4, 64);
            part += __shfl_xor(part, 8, 64);
            if (ln == 0) {
                int m = w * 64 + mt * 16 + quad * 4 + r;
                out[(size_t)(b0 + m) * C_ + c] = expf(-0.5f * part);
            }
        }
    }
}

extern "C" void kernel_launch(void* const* d_in, const int* in_sizes, int n_in,
                              void* d_out, int out_size, void* d_ws, size_t ws_size,
                              hipStream_t stream) {
    const float* x  = (const float*)d_in[0];
    const float* W  = (const float*)d_in[1];
    const float* b  = (const float*)d_in[2];
    const float* u  = (const float*)d_in[3];
    const float* cc = (const float*)d_in[4];
    float* out = (float*)d_out;

    // workspace layout (all 16B aligned)
    char* ws = (char*)d_ws;
    _Float16* Wh   = (_Float16*)ws;                               // 52,428,800 B
    _Float16* xh   = (_Float16*)(ws + (size_t)C_ * F_ * E_ * 2);  //  2,097,152 B
    float*    rsig = (float*)(ws + (size_t)C_ * F_ * E_ * 2 + (size_t)B_ * E_ * 2); // 400 B

    k_conv_x<<<B_, 256, 0, stream>>>(x, xh);
    k_conv_w<<<800, 256, 0, stream>>>(W, Wh);
    k_gramsig<<<C_, 256, 0, stream>>>(Wh, u, rsig);

    dim3 grid(B_ / 128, C_);
    k_main<<<grid, 128, 0, stream>>>(xh, Wh, b, cc, rsig, out);
}

// Round 6
// 231.971 us; speedup vs baseline: 1.6995x; 1.1032x over previous
//
#include <hip/hip_runtime.h>
#include <math.h>

#define B_ 512
#define C_ 100
#define E_ 2048
#define F_ 128

typedef _Float16 f16x8 __attribute__((ext_vector_type(8)));
typedef float    f32x4 __attribute__((ext_vector_type(4)));

#define AS1q __attribute__((address_space(1)))
#define AS3q __attribute__((address_space(3)))

// async global->LDS DMA, 16 B per lane; LDS dest = wave-uniform base + lane*16
__device__ __forceinline__ void gl_lds16(const void* g, void* lds_base) {
    __builtin_amdgcn_global_load_lds((const AS1q void*)g, (AS3q void*)lds_base, 16, 0, 0);
}

// ---------------- kernel 0: fp32 -> fp16 conversion for W (800 blocks) and x (32 blocks)
__global__ __launch_bounds__(256)
void k_conv(const float* __restrict__ W, _Float16* __restrict__ Wh,
            const float* __restrict__ x, _Float16* __restrict__ xh) {
    const int blk = blockIdx.x;
    const float* src; _Float16* dst; size_t base;
    if (blk < 800) { src = W; dst = Wh; base = (size_t)blk * 32768 + threadIdx.x * 8; }
    else           { src = x; dst = xh; base = (size_t)(blk - 800) * 32768 + threadIdx.x * 8; }
#pragma unroll
    for (int it = 0; it < 16; ++it) {
        const size_t idx = base + (size_t)it * 2048;
        float4 a = *(const float4*)(src + idx);
        float4 b = *(const float4*)(src + idx + 4);
        f16x8 h;
        h[0] = (_Float16)a.x; h[1] = (_Float16)a.y; h[2] = (_Float16)a.z; h[3] = (_Float16)a.w;
        h[4] = (_Float16)b.x; h[5] = (_Float16)b.y; h[6] = (_Float16)b.z; h[7] = (_Float16)b.w;
        *(f16x8*)(dst + idx) = h;
    }
}

// ---------------- kernel 1: y[c] += G_chunk * u, G_chunk = Wh[:,k0:k0+256] Wh^T[...]
// grid (8 chunks, C_), block 256 = 4 waves (2x2). Wave owns 64x64 of G.
__global__ __launch_bounds__(256, 2)
void k_gram_y(const _Float16* __restrict__ Wh, const float* __restrict__ u,
              float* __restrict__ y) {
    const int chunk = blockIdx.x;
    const int c  = blockIdx.y;
    const int t  = threadIdx.x;
    const int w  = t >> 6;
    const int l  = t & 63;
    const int wm = w & 1, wn = w >> 1;
    const int ln = l & 15, quad = l >> 4;

    __shared__ _Float16 Ts[128 * 64];   // 16 KB

    f32x4 acc[4][4];
#pragma unroll
    for (int mt = 0; mt < 4; ++mt)
#pragma unroll
        for (int nt = 0; nt < 4; ++nt) acc[mt][nt] = (f32x4){0.f, 0.f, 0.f, 0.f};

    const int lr = l >> 3;               // sub-row within an 8-row DMA instr
    const int lg = (l & 7) ^ lr;         // swizzled source chunk
    const _Float16* wsrc = Wh + ((size_t)c * F_ + w * 32 + lr) * E_ + lg * 8;
    const int kbase = chunk * 256;

    for (int k0 = kbase; k0 < kbase + 256; k0 += 64) {
#pragma unroll
        for (int q = 0; q < 4; ++q)
            gl_lds16(wsrc + (size_t)q * 8 * E_ + k0, &Ts[(w * 4 + q) * 512]);
        __syncthreads();

#pragma unroll
        for (int kk = 0; kk < 64; kk += 32) {
            const int g0 = (kk >> 3) + quad;
            const int sw = (g0 ^ (ln & 7)) * 8;
            f16x8 av[4], bv[4];
#pragma unroll
            for (int mt = 0; mt < 4; ++mt)
                av[mt] = *(const f16x8*)&Ts[(wm * 64 + mt * 16 + ln) * 64 + sw];
#pragma unroll
            for (int nt = 0; nt < 4; ++nt)
                bv[nt] = *(const f16x8*)&Ts[(wn * 64 + nt * 16 + ln) * 64 + sw];
#pragma unroll
            for (int mt = 0; mt < 4; ++mt)
#pragma unroll
                for (int nt = 0; nt < 4; ++nt)
                    acc[mt][nt] = __builtin_amdgcn_mfma_f32_16x16x32_f16(
                        av[mt], bv[nt], acc[mt][nt], 0, 0, 0);
        }
        __syncthreads();
    }

    // y_chunk = G_chunk * u ; atomicAdd into y[c]
    const float* uc = u + (size_t)c * F_;
    float un[4];
#pragma unroll
    for (int nt = 0; nt < 4; ++nt) un[nt] = uc[wn * 64 + nt * 16 + ln];

#pragma unroll
    for (int mt = 0; mt < 4; ++mt) {
#pragma unroll
        for (int r = 0; r < 4; ++r) {
            float py = acc[mt][0][r] * un[0];
            py = fmaf(acc[mt][1][r], un[1], py);
            py = fmaf(acc[mt][2][r], un[2], py);
            py = fmaf(acc[mt][3][r], un[3], py);
            py += __shfl_xor(py, 1, 64);
            py += __shfl_xor(py, 2, 64);
            py += __shfl_xor(py, 4, 64);
            py += __shfl_xor(py, 8, 64);
            if (ln == 0) {
                int m = wm * 64 + mt * 16 + quad * 4 + r;
                atomicAdd(&y[(size_t)c * F_ + m], py);
            }
        }
    }
}

// ---------------- kernel 2: rsig[c] = sqrt(u.y / y.y)
__global__ __launch_bounds__(64)
void k_rsig(const float* __restrict__ u, const float* __restrict__ y,
            float* __restrict__ rsig) {
    const int c = blockIdx.x;
    const int l = threadIdx.x;
    float y0 = y[(size_t)c * F_ + l],      y1 = y[(size_t)c * F_ + 64 + l];
    float u0 = u[(size_t)c * F_ + l],      u1 = u[(size_t)c * F_ + 64 + l];
    float nv = u0 * y0 + u1 * y1;
    float ts = y0 * y0 + y1 * y1;
    for (int off = 32; off; off >>= 1) {
        nv += __shfl_down(nv, off, 64);
        ts += __shfl_down(ts, off, 64);
    }
    if (l == 0) rsig[c] = sqrtf(nv / ts);
}

// ---------------- kernel 3: fused MFMA GEMM + dist2 + exp  (m97 structure)
// grid (4 b-tiles, 100 classes), block 256 = 4 waves (2x2); M=128, N=128, BK=64.
// Wave (wm,wn) owns rows [wm*64,+64) x cols [wn*64,+64): 4x4 tiles of 16x16.
__global__ __launch_bounds__(256, 2)
void k_main(const _Float16* __restrict__ xh, const _Float16* __restrict__ Wh,
            const float* __restrict__ bias, const float* __restrict__ cent,
            const float* __restrict__ rsig, float* __restrict__ out) {
    const int c  = blockIdx.y;
    const int b0 = blockIdx.x * 128;
    const int t  = threadIdx.x;
    const int w  = t >> 6;
    const int l  = t & 63;
    const int wm = w & 1, wn = w >> 1;
    const int ln = l & 15, quad = l >> 4;

    __shared__ _Float16 Xs[128 * 64];   // 16 KB
    __shared__ _Float16 Ws[128 * 64];   // 16 KB

    f32x4 acc[4][4];
#pragma unroll
    for (int mt = 0; mt < 4; ++mt)
#pragma unroll
        for (int nt = 0; nt < 4; ++nt) acc[mt][nt] = (f32x4){0.f, 0.f, 0.f, 0.f};

    const int lr = l >> 3;
    const int lg = (l & 7) ^ lr;
    // wave w stages X rows [w*32,+32) and W rows [w*32,+32), 4 DMA instrs each
    const _Float16* xsrc = xh + (size_t)(b0 + w * 32 + lr) * E_ + lg * 8;
    const _Float16* wsrc = Wh + ((size_t)c * F_ + w * 32 + lr) * E_ + lg * 8;

    for (int k0 = 0; k0 < E_; k0 += 64) {
#pragma unroll
        for (int q = 0; q < 4; ++q)
            gl_lds16(xsrc + (size_t)q * 8 * E_ + k0, &Xs[(w * 4 + q) * 512]);
#pragma unroll
        for (int q = 0; q < 4; ++q)
            gl_lds16(wsrc + (size_t)q * 8 * E_ + k0, &Ws[(w * 4 + q) * 512]);
        __syncthreads();

#pragma unroll
        for (int kk = 0; kk < 64; kk += 32) {
            const int g0 = (kk >> 3) + quad;
            const int sw = (g0 ^ (ln & 7)) * 8;
            f16x8 av[4], bv[4];
#pragma unroll
            for (int mt = 0; mt < 4; ++mt)
                av[mt] = *(const f16x8*)&Xs[(wm * 64 + mt * 16 + ln) * 64 + sw];
#pragma unroll
            for (int nt = 0; nt < 4; ++nt)
                bv[nt] = *(const f16x8*)&Ws[(wn * 64 + nt * 16 + ln) * 64 + sw];
#pragma unroll
            for (int mt = 0; mt < 4; ++mt)
#pragma unroll
                for (int nt = 0; nt < 4; ++nt)
                    acc[mt][nt] = __builtin_amdgcn_mfma_f32_16x16x32_f16(
                        av[mt], bv[nt], acc[mt][nt], 0, 0, 0);
        }
        __syncthreads();
    }

    const float rsigma = rsig[c];

    float bi[4], ce[4];
#pragma unroll
    for (int nt = 0; nt < 4; ++nt) {
        int f = wn * 64 + nt * 16 + ln;
        bi[nt] = bias[c * F_ + f];
        ce[nt] = cent[c * F_ + f];
    }

    float* red = (float*)&Xs[0];        // [128][2] floats, reuse LDS (post-barrier)

#pragma unroll
    for (int mt = 0; mt < 4; ++mt) {
#pragma unroll
        for (int r = 0; r < 4; ++r) {
            float part = 0.f;
#pragma unroll
            for (int nt = 0; nt < 4; ++nt) {
                float z = fmaf(acc[mt][nt][r], rsigma, bi[nt]);
                float d = ce[nt] - z;
                part = fmaf(d, d, part);
            }
            part += __shfl_xor(part, 1, 64);
            part += __shfl_xor(part, 2, 64);
            part += __shfl_xor(part, 4, 64);
            part += __shfl_xor(part, 8, 64);
            if (ln == 0) {
                int m = wm * 64 + mt * 16 + quad * 4 + r;
                red[m * 2 + wn] = part;
            }
        }
    }
    __syncthreads();
    if (t < 128) {
        float d2 = red[t * 2] + red[t * 2 + 1];
        out[(size_t)(b0 + t) * C_ + c] = expf(-0.5f * d2);
    }
}

extern "C" void kernel_launch(void* const* d_in, const int* in_sizes, int n_in,
                              void* d_out, int out_size, void* d_ws, size_t ws_size,
                              hipStream_t stream) {
    const float* x  = (const float*)d_in[0];
    const float* W  = (const float*)d_in[1];
    const float* b  = (const float*)d_in[2];
    const float* u  = (const float*)d_in[3];
    const float* cc = (const float*)d_in[4];
    float* out = (float*)d_out;

    // workspace layout (all 16B aligned)
    char* ws = (char*)d_ws;
    _Float16* Wh   = (_Float16*)ws;                               // 52,428,800 B
    _Float16* xh   = (_Float16*)(ws + (size_t)C_ * F_ * E_ * 2);  //  2,097,152 B
    float*    yv   = (float*)(ws + (size_t)C_ * F_ * E_ * 2 + (size_t)B_ * E_ * 2); // C*F floats
    float*    rsig = yv + (size_t)C_ * F_;                        // C floats

    hipMemsetAsync(yv, 0, (size_t)C_ * F_ * sizeof(float), stream);

    k_conv<<<832, 256, 0, stream>>>(W, Wh, x, xh);

    dim3 ggrid(8, C_);
    k_gram_y<<<ggrid, 256, 0, stream>>>(Wh, u, yv);
    k_rsig<<<C_, 64, 0, stream>>>(u, yv, rsig);

    dim3 grid(B_ / 128, C_);
    k_main<<<grid, 256, 0, stream>>>(xh, Wh, b, cc, rsig, out);
}

// Round 7
// 221.838 us; speedup vs baseline: 1.7771x; 1.0457x over previous
//
#include <hip/hip_runtime.h>
#include <math.h>

#define B_ 512
#define C_ 100
#define E_ 2048
#define F_ 128

typedef _Float16 f16x8 __attribute__((ext_vector_type(8)));
typedef float    f32x4 __attribute__((ext_vector_type(4)));

#define AS1q __attribute__((address_space(1)))
#define AS3q __attribute__((address_space(3)))

// async global->LDS DMA, 16 B per lane; LDS dest = wave-uniform base + lane*16
__device__ __forceinline__ void gl_lds16(const void* g, void* lds_base) {
    __builtin_amdgcn_global_load_lds((const AS1q void*)g, (AS3q void*)lds_base, 16, 0, 0);
}

// ---------------- kernel 1: fused W conversion + per-class Gram-chunk + y-chunk
// blocks 0..799: (c = b/8, chunk = b%8). Reads fp32 W[c, :, chunk*256 +: 256],
//   converts -> Wh (global) and -> LDS (fp16, XOR-swizzled), MFMA Gram G_chunk,
//   stores y_chunk = G_chunk * u[c] to ychunks[chunk][c][:]  (no atomics).
// blocks 800..831: x fp32 -> fp16.
__global__ __launch_bounds__(256, 2)
void k_gram(const float* __restrict__ W, _Float16* __restrict__ Wh,
            const float* __restrict__ x, _Float16* __restrict__ xh,
            const float* __restrict__ u, float* __restrict__ ychunks) {
    const int b = blockIdx.x;
    const int t = threadIdx.x;

    if (b >= 800) {   // ---- x conversion
        const size_t base = (size_t)(b - 800) * 32768 + t * 8;
#pragma unroll
        for (int it = 0; it < 16; ++it) {
            const size_t idx = base + (size_t)it * 2048;
            float4 a  = *(const float4*)(x + idx);
            float4 bb = *(const float4*)(x + idx + 4);
            f16x8 h;
            h[0] = (_Float16)a.x;  h[1] = (_Float16)a.y;  h[2] = (_Float16)a.z;  h[3] = (_Float16)a.w;
            h[4] = (_Float16)bb.x; h[5] = (_Float16)bb.y; h[6] = (_Float16)bb.z; h[7] = (_Float16)bb.w;
            *(f16x8*)(xh + idx) = h;
        }
        return;
    }

    const int c     = b >> 3;
    const int chunk = b & 7;
    const int w  = t >> 6;
    const int l  = t & 63;
    const int wm = w & 1, wn = w >> 1;
    const int ln = l & 15, quad = l >> 4;

    __shared__ _Float16 Ts[128 * 64];   // 16 KB

    f32x4 acc[4][4];
#pragma unroll
    for (int mt = 0; mt < 4; ++mt)
#pragma unroll
        for (int nt = 0; nt < 4; ++nt) acc[mt][nt] = (f32x4){0.f, 0.f, 0.f, 0.f};

    // staging: row r = t>>1 (2 threads/row), 32 consecutive floats each
    const int r  = t >> 1;
    const int cb = (t & 1) * 32;            // float/half offset in 64-wide window
    const float* wsrc = W  + ((size_t)c * F_ + r) * E_ + cb;
    _Float16*    wdst = Wh + ((size_t)c * F_ + r) * E_ + cb;
    const int kbase = chunk * 256;

    for (int k0 = kbase; k0 < kbase + 256; k0 += 64) {
        // load 32 fp32, convert to 4 x f16x8
        float4 f[8];
#pragma unroll
        for (int j = 0; j < 8; ++j) f[j] = *(const float4*)(wsrc + k0 + j * 4);
        f16x8 h[4];
#pragma unroll
        for (int j = 0; j < 4; ++j) {
            h[j][0] = (_Float16)f[2*j].x;   h[j][1] = (_Float16)f[2*j].y;
            h[j][2] = (_Float16)f[2*j].z;   h[j][3] = (_Float16)f[2*j].w;
            h[j][4] = (_Float16)f[2*j+1].x; h[j][5] = (_Float16)f[2*j+1].y;
            h[j][6] = (_Float16)f[2*j+1].z; h[j][7] = (_Float16)f[2*j+1].w;
        }
        // global fp16 store
#pragma unroll
        for (int j = 0; j < 4; ++j) *(f16x8*)(wdst + k0 + j * 8) = h[j];

        // LDS store, chunk g at slot g^(r&7)  (matches MFMA read swizzle)
        __syncthreads();                    // prior MFMA reads done before overwrite
#pragma unroll
        for (int j = 0; j < 4; ++j) {
            const int g = (cb >> 3) + j;
            *(f16x8*)&Ts[r * 64 + ((g ^ (r & 7)) << 3)] = h[j];
        }
        __syncthreads();

        // Gram MFMA phase: A and B fragments from the same tile
#pragma unroll
        for (int kk = 0; kk < 64; kk += 32) {
            const int g0 = (kk >> 3) + quad;
            const int sw = (g0 ^ (ln & 7)) * 8;
            f16x8 av[4], bv[4];
#pragma unroll
            for (int mt = 0; mt < 4; ++mt)
                av[mt] = *(const f16x8*)&Ts[(wm * 64 + mt * 16 + ln) * 64 + sw];
#pragma unroll
            for (int nt = 0; nt < 4; ++nt)
                bv[nt] = *(const f16x8*)&Ts[(wn * 64 + nt * 16 + ln) * 64 + sw];
#pragma unroll
            for (int mt = 0; mt < 4; ++mt)
#pragma unroll
                for (int nt = 0; nt < 4; ++nt)
                    acc[mt][nt] = __builtin_amdgcn_mfma_f32_16x16x32_f16(
                        av[mt], bv[nt], acc[mt][nt], 0, 0, 0);
        }
    }

    // y_chunk = G_chunk * u ; combine the two wn-halves via LDS, plain store
    const float* uc = u + (size_t)c * F_;
    float un[4];
#pragma unroll
    for (int nt = 0; nt < 4; ++nt) un[nt] = uc[wn * 64 + nt * 16 + ln];

    __syncthreads();
    float* red = (float*)&Ts[0];        // [128][2] floats

#pragma unroll
    for (int mt = 0; mt < 4; ++mt) {
#pragma unroll
        for (int rr = 0; rr < 4; ++rr) {
            float py = acc[mt][0][rr] * un[0];
            py = fmaf(acc[mt][1][rr], un[1], py);
            py = fmaf(acc[mt][2][rr], un[2], py);
            py = fmaf(acc[mt][3][rr], un[3], py);
            py += __shfl_xor(py, 1, 64);
            py += __shfl_xor(py, 2, 64);
            py += __shfl_xor(py, 4, 64);
            py += __shfl_xor(py, 8, 64);
            if (ln == 0) {
                int m = wm * 64 + mt * 16 + quad * 4 + rr;
                red[m * 2 + wn] = py;
            }
        }
    }
    __syncthreads();
    if (t < 128) {
        float yv = red[t * 2] + red[t * 2 + 1];
        ychunks[((size_t)chunk * C_ + c) * F_ + t] = yv;
    }
}

// ---------------- kernel 2: fused MFMA GEMM + dist2 + exp, rsig computed inline
// grid (4 b-tiles, 100 classes), block 256 = 4 waves (2x2); M=128, N=128, BK=64.
__global__ __launch_bounds__(256, 2)
void k_main(const _Float16* __restrict__ xh, const _Float16* __restrict__ Wh,
            const float* __restrict__ bias, const float* __restrict__ cent,
            const float* __restrict__ u, const float* __restrict__ ychunks,
            float* __restrict__ out) {
    const int c  = blockIdx.y;
    const int b0 = blockIdx.x * 128;
    const int t  = threadIdx.x;
    const int w  = t >> 6;
    const int l  = t & 63;
    const int wm = w & 1, wn = w >> 1;
    const int ln = l & 15, quad = l >> 4;

    __shared__ _Float16 Xs[128 * 64];   // 16 KB
    __shared__ _Float16 Ws[128 * 64];   // 16 KB
    __shared__ float red2[2][2];
    __shared__ float s_rsig;

    // ---- inline rsig = sqrt(u.y / y.y),  y[f] = sum_chunk ychunks[chunk][c][f]
    if (t < 128) {
        float yf = 0.f;
#pragma unroll
        for (int ch = 0; ch < 8; ++ch)
            yf += ychunks[((size_t)ch * C_ + c) * F_ + t];
        float nvp = u[(size_t)c * F_ + t] * yf;
        float tsp = yf * yf;
        for (int off = 32; off; off >>= 1) {
            nvp += __shfl_down(nvp, off, 64);
            tsp += __shfl_down(tsp, off, 64);
        }
        if (l == 0) { red2[w][0] = nvp; red2[w][1] = tsp; }
    }
    __syncthreads();
    if (t == 0) s_rsig = sqrtf((red2[0][0] + red2[1][0]) / (red2[0][1] + red2[1][1]));
    // s_rsig visibility to all threads is guaranteed by the K-loop barriers below.

    f32x4 acc[4][4];
#pragma unroll
    for (int mt = 0; mt < 4; ++mt)
#pragma unroll
        for (int nt = 0; nt < 4; ++nt) acc[mt][nt] = (f32x4){0.f, 0.f, 0.f, 0.f};

    const int lr = l >> 3;
    const int lg = (l & 7) ^ lr;
    // wave w stages X rows [w*32,+32) and W rows [w*32,+32), 4 DMA instrs each
    const _Float16* xsrc = xh + (size_t)(b0 + w * 32 + lr) * E_ + lg * 8;
    const _Float16* wsrc = Wh + ((size_t)c * F_ + w * 32 + lr) * E_ + lg * 8;

    for (int k0 = 0; k0 < E_; k0 += 64) {
#pragma unroll
        for (int q = 0; q < 4; ++q)
            gl_lds16(xsrc + (size_t)q * 8 * E_ + k0, &Xs[(w * 4 + q) * 512]);
#pragma unroll
        for (int q = 0; q < 4; ++q)
            gl_lds16(wsrc + (size_t)q * 8 * E_ + k0, &Ws[(w * 4 + q) * 512]);
        __syncthreads();

#pragma unroll
        for (int kk = 0; kk < 64; kk += 32) {
            const int g0 = (kk >> 3) + quad;
            const int sw = (g0 ^ (ln & 7)) * 8;
            f16x8 av[4], bv[4];
#pragma unroll
            for (int mt = 0; mt < 4; ++mt)
                av[mt] = *(const f16x8*)&Xs[(wm * 64 + mt * 16 + ln) * 64 + sw];
#pragma unroll
            for (int nt = 0; nt < 4; ++nt)
                bv[nt] = *(const f16x8*)&Ws[(wn * 64 + nt * 16 + ln) * 64 + sw];
#pragma unroll
            for (int mt = 0; mt < 4; ++mt)
#pragma unroll
                for (int nt = 0; nt < 4; ++nt)
                    acc[mt][nt] = __builtin_amdgcn_mfma_f32_16x16x32_f16(
                        av[mt], bv[nt], acc[mt][nt], 0, 0, 0);
        }
        __syncthreads();
    }

    const float rsigma = s_rsig;

    float bi[4], ce[4];
#pragma unroll
    for (int nt = 0; nt < 4; ++nt) {
        int f = wn * 64 + nt * 16 + ln;
        bi[nt] = bias[c * F_ + f];
        ce[nt] = cent[c * F_ + f];
    }

    float* red = (float*)&Xs[0];        // [128][2] floats, reuse LDS (post-barrier)

#pragma unroll
    for (int mt = 0; mt < 4; ++mt) {
#pragma unroll
        for (int r = 0; r < 4; ++r) {
            float part = 0.f;
#pragma unroll
            for (int nt = 0; nt < 4; ++nt) {
                float z = fmaf(acc[mt][nt][r], rsigma, bi[nt]);
                float d = ce[nt] - z;
                part = fmaf(d, d, part);
            }
            part += __shfl_xor(part, 1, 64);
            part += __shfl_xor(part, 2, 64);
            part += __shfl_xor(part, 4, 64);
            part += __shfl_xor(part, 8, 64);
            if (ln == 0) {
                int m = wm * 64 + mt * 16 + quad * 4 + r;
                red[m * 2 + wn] = part;
            }
        }
    }
    __syncthreads();
    if (t < 128) {
        float d2 = red[t * 2] + red[t * 2 + 1];
        out[(size_t)(b0 + t) * C_ + c] = expf(-0.5f * d2);
    }
}

extern "C" void kernel_launch(void* const* d_in, const int* in_sizes, int n_in,
                              void* d_out, int out_size, void* d_ws, size_t ws_size,
                              hipStream_t stream) {
    const float* x  = (const float*)d_in[0];
    const float* W  = (const float*)d_in[1];
    const float* b  = (const float*)d_in[2];
    const float* u  = (const float*)d_in[3];
    const float* cc = (const float*)d_in[4];
    float* out = (float*)d_out;

    // workspace layout (all 16B aligned)
    char* ws = (char*)d_ws;
    _Float16* Wh      = (_Float16*)ws;                                // 52,428,800 B
    _Float16* xh      = (_Float16*)(ws + (size_t)C_ * F_ * E_ * 2);   //  2,097,152 B
    float*    ychunks = (float*)(ws + (size_t)C_ * F_ * E_ * 2 + (size_t)B_ * E_ * 2); // 409,600 B

    k_gram<<<832, 256, 0, stream>>>(W, Wh, x, xh, u, ychunks);

    dim3 grid(B_ / 128, C_);
    k_main<<<grid, 256, 0, stream>>>(xh, Wh, b, cc, u, ychunks, out);
}

// Round 8
// 218.201 us; speedup vs baseline: 1.8067x; 1.0167x over previous
//
#include <hip/hip_runtime.h>
#include <math.h>

#define B_ 512
#define C_ 100
#define E_ 2048
#define F_ 128
#define NCHUNK 16
#define CHUNKW 128   // k-width per gram block

typedef _Float16 f16x8 __attribute__((ext_vector_type(8)));
typedef float    f32x4 __attribute__((ext_vector_type(4)));

#define AS1q __attribute__((address_space(1)))
#define AS3q __attribute__((address_space(3)))

// async global->LDS DMA, 16 B per lane; LDS dest = wave-uniform base + lane*16
__device__ __forceinline__ void gl_lds16(const void* g, void* lds_base) {
    __builtin_amdgcn_global_load_lds((const AS1q void*)g, (AS3q void*)lds_base, 16, 0, 0);
}

// ---------------- kernel 1: fused W conversion + per-class Gram-chunk + y-chunk
// blocks 0..1599: (c = b/16, chunk = b%16), k-window = chunk*128 +: 128.
//   fp32 W -> fp16 Wh (global) + fp16 LDS tile (XOR-swizzled) -> Gram MFMA ->
//   y_chunk = G_chunk * u stored to ychunks[chunk][c][:]  (no atomics).
// blocks 1600..1631: x fp32 -> fp16.
__global__ __launch_bounds__(256, 3)
void k_gram(const float* __restrict__ W, _Float16* __restrict__ Wh,
            const float* __restrict__ x, _Float16* __restrict__ xh,
            const float* __restrict__ u, float* __restrict__ ychunks) {
    const int b = blockIdx.x;
    const int t = threadIdx.x;

    if (b >= 1600) {   // ---- x conversion
        const size_t base = (size_t)(b - 1600) * 32768 + t * 8;
#pragma unroll
        for (int it = 0; it < 16; ++it) {
            const size_t idx = base + (size_t)it * 2048;
            float4 a  = *(const float4*)(x + idx);
            float4 bb = *(const float4*)(x + idx + 4);
            f16x8 h;
            h[0] = (_Float16)a.x;  h[1] = (_Float16)a.y;  h[2] = (_Float16)a.z;  h[3] = (_Float16)a.w;
            h[4] = (_Float16)bb.x; h[5] = (_Float16)bb.y; h[6] = (_Float16)bb.z; h[7] = (_Float16)bb.w;
            *(f16x8*)(xh + idx) = h;
        }
        return;
    }

    const int c     = b >> 4;
    const int chunk = b & 15;
    const int w  = t >> 6;
    const int l  = t & 63;
    const int wm = w & 1, wn = w >> 1;
    const int ln = l & 15, quad = l >> 4;

    __shared__ _Float16 Ts[128 * 64];   // 16 KB

    f32x4 acc[4][4];
#pragma unroll
    for (int mt = 0; mt < 4; ++mt)
#pragma unroll
        for (int nt = 0; nt < 4; ++nt) acc[mt][nt] = (f32x4){0.f, 0.f, 0.f, 0.f};

    // staging: row r = t>>1 (2 threads/row), 32 consecutive floats each
    const int r  = t >> 1;
    const int cb = (t & 1) * 32;
    const float* wsrc = W  + ((size_t)c * F_ + r) * E_ + cb;
    _Float16*    wdst = Wh + ((size_t)c * F_ + r) * E_ + cb;
    const int kbase = chunk * CHUNKW;

    // prologue: load iteration 0 (32 fp32 into 8 live float4)
    float4 f[8];
#pragma unroll
    for (int j = 0; j < 8; ++j) f[j] = *(const float4*)(wsrc + kbase + j * 4);

#pragma unroll
    for (int i = 0; i < CHUNKW / 64; ++i) {
        const int k0 = kbase + i * 64;
        // convert
        f16x8 h[4];
#pragma unroll
        for (int j = 0; j < 4; ++j) {
            h[j][0] = (_Float16)f[2*j].x;   h[j][1] = (_Float16)f[2*j].y;
            h[j][2] = (_Float16)f[2*j].z;   h[j][3] = (_Float16)f[2*j].w;
            h[j][4] = (_Float16)f[2*j+1].x; h[j][5] = (_Float16)f[2*j+1].y;
            h[j][6] = (_Float16)f[2*j+1].z; h[j][7] = (_Float16)f[2*j+1].w;
        }
        __syncthreads();                 // prior MFMA reads done before overwrite
#pragma unroll
        for (int j = 0; j < 4; ++j) {
            const int g = (cb >> 3) + j;
            *(f16x8*)&Ts[r * 64 + ((g ^ (r & 7)) << 3)] = h[j];
        }
        __syncthreads();

        // issue global Wh store + next iteration's loads; latency hides under MFMA
#pragma unroll
        for (int j = 0; j < 4; ++j) *(f16x8*)(wdst + k0 + j * 8) = h[j];
        if (i + 1 < CHUNKW / 64) {
#pragma unroll
            for (int j = 0; j < 8; ++j) f[j] = *(const float4*)(wsrc + k0 + 64 + j * 4);
        }

        // Gram MFMA phase: A and B fragments from the same tile
#pragma unroll
        for (int kk = 0; kk < 64; kk += 32) {
            const int g0 = (kk >> 3) + quad;
            const int sw = (g0 ^ (ln & 7)) * 8;
            f16x8 av[4], bv[4];
#pragma unroll
            for (int mt = 0; mt < 4; ++mt)
                av[mt] = *(const f16x8*)&Ts[(wm * 64 + mt * 16 + ln) * 64 + sw];
#pragma unroll
            for (int nt = 0; nt < 4; ++nt)
                bv[nt] = *(const f16x8*)&Ts[(wn * 64 + nt * 16 + ln) * 64 + sw];
#pragma unroll
            for (int mt = 0; mt < 4; ++mt)
#pragma unroll
                for (int nt = 0; nt < 4; ++nt)
                    acc[mt][nt] = __builtin_amdgcn_mfma_f32_16x16x32_f16(
                        av[mt], bv[nt], acc[mt][nt], 0, 0, 0);
        }
    }

    // y_chunk = G_chunk * u ; combine the two wn-halves via LDS, plain store
    const float* uc = u + (size_t)c * F_;
    float un[4];
#pragma unroll
    for (int nt = 0; nt < 4; ++nt) un[nt] = uc[wn * 64 + nt * 16 + ln];

    __syncthreads();
    float* red = (float*)&Ts[0];        // [128][2] floats

#pragma unroll
    for (int mt = 0; mt < 4; ++mt) {
#pragma unroll
        for (int rr = 0; rr < 4; ++rr) {
            float py = acc[mt][0][rr] * un[0];
            py = fmaf(acc[mt][1][rr], un[1], py);
            py = fmaf(acc[mt][2][rr], un[2], py);
            py = fmaf(acc[mt][3][rr], un[3], py);
            py += __shfl_xor(py, 1, 64);
            py += __shfl_xor(py, 2, 64);
            py += __shfl_xor(py, 4, 64);
            py += __shfl_xor(py, 8, 64);
            if (ln == 0) {
                int m = wm * 64 + mt * 16 + quad * 4 + rr;
                red[m * 2 + wn] = py;
            }
        }
    }
    __syncthreads();
    if (t < 128) {
        float yv = red[t * 2] + red[t * 2 + 1];
        ychunks[((size_t)chunk * C_ + c) * F_ + t] = yv;
    }
}

// ---------------- kernel 2: fused MFMA GEMM + dist2 + exp, rsig computed inline
// grid (4 b-tiles, 100 classes), block 256 = 4 waves (2x2); M=128, N=128, BK=64.
__global__ __launch_bounds__(256, 2)
void k_main(const _Float16* __restrict__ xh, const _Float16* __restrict__ Wh,
            const float* __restrict__ bias, const float* __restrict__ cent,
            const float* __restrict__ u, const float* __restrict__ ychunks,
            float* __restrict__ out) {
    const int c  = blockIdx.y;
    const int b0 = blockIdx.x * 128;
    const int t  = threadIdx.x;
    const int w  = t >> 6;
    const int l  = t & 63;
    const int wm = w & 1, wn = w >> 1;
    const int ln = l & 15, quad = l >> 4;

    __shared__ _Float16 Xs[128 * 64];   // 16 KB
    __shared__ _Float16 Ws[128 * 64];   // 16 KB
    __shared__ float red2[2][2];
    __shared__ float s_rsig;

    // ---- inline rsig = sqrt(u.y / y.y),  y[f] = sum_chunk ychunks[chunk][c][f]
    if (t < 128) {
        float yf = 0.f;
#pragma unroll
        for (int ch = 0; ch < NCHUNK; ++ch)
            yf += ychunks[((size_t)ch * C_ + c) * F_ + t];
        float nvp = u[(size_t)c * F_ + t] * yf;
        float tsp = yf * yf;
        for (int off = 32; off; off >>= 1) {
            nvp += __shfl_down(nvp, off, 64);
            tsp += __shfl_down(tsp, off, 64);
        }
        if (l == 0) { red2[w][0] = nvp; red2[w][1] = tsp; }
    }
    __syncthreads();
    if (t == 0) s_rsig = sqrtf((red2[0][0] + red2[1][0]) / (red2[0][1] + red2[1][1]));
    // s_rsig visibility to all threads is guaranteed by the K-loop barriers below.

    f32x4 acc[4][4];
#pragma unroll
    for (int mt = 0; mt < 4; ++mt)
#pragma unroll
        for (int nt = 0; nt < 4; ++nt) acc[mt][nt] = (f32x4){0.f, 0.f, 0.f, 0.f};

    const int lr = l >> 3;
    const int lg = (l & 7) ^ lr;
    // wave w stages X rows [w*32,+32) and W rows [w*32,+32), 4 DMA instrs each
    const _Float16* xsrc = xh + (size_t)(b0 + w * 32 + lr) * E_ + lg * 8;
    const _Float16* wsrc = Wh + ((size_t)c * F_ + w * 32 + lr) * E_ + lg * 8;

    for (int k0 = 0; k0 < E_; k0 += 64) {
#pragma unroll
        for (int q = 0; q < 4; ++q)
            gl_lds16(xsrc + (size_t)q * 8 * E_ + k0, &Xs[(w * 4 + q) * 512]);
#pragma unroll
        for (int q = 0; q < 4; ++q)
            gl_lds16(wsrc + (size_t)q * 8 * E_ + k0, &Ws[(w * 4 + q) * 512]);
        __syncthreads();

#pragma unroll
        for (int kk = 0; kk < 64; kk += 32) {
            const int g0 = (kk >> 3) + quad;
            const int sw = (g0 ^ (ln & 7)) * 8;
            f16x8 av[4], bv[4];
#pragma unroll
            for (int mt = 0; mt < 4; ++mt)
                av[mt] = *(const f16x8*)&Xs[(wm * 64 + mt * 16 + ln) * 64 + sw];
#pragma unroll
            for (int nt = 0; nt < 4; ++nt)
                bv[nt] = *(const f16x8*)&Ws[(wn * 64 + nt * 16 + ln) * 64 + sw];
#pragma unroll
            for (int mt = 0; mt < 4; ++mt)
#pragma unroll
                for (int nt = 0; nt < 4; ++nt)
                    acc[mt][nt] = __builtin_amdgcn_mfma_f32_16x16x32_f16(
                        av[mt], bv[nt], acc[mt][nt], 0, 0, 0);
        }
        __syncthreads();
    }

    const float rsigma = s_rsig;

    float bi[4], ce[4];
#pragma unroll
    for (int nt = 0; nt < 4; ++nt) {
        int f = wn * 64 + nt * 16 + ln;
        bi[nt] = bias[c * F_ + f];
        ce[nt] = cent[c * F_ + f];
    }

    float* red = (float*)&Xs[0];        // [128][2] floats, reuse LDS (post-barrier)

#pragma unroll
    for (int mt = 0; mt < 4; ++mt) {
#pragma unroll
        for (int r = 0; r < 4; ++r) {
            float part = 0.f;
#pragma unroll
            for (int nt = 0; nt < 4; ++nt) {
                float z = fmaf(acc[mt][nt][r], rsigma, bi[nt]);
                float d = ce[nt] - z;
                part = fmaf(d, d, part);
            }
            part += __shfl_xor(part, 1, 64);
            part += __shfl_xor(part, 2, 64);
            part += __shfl_xor(part, 4, 64);
            part += __shfl_xor(part, 8, 64);
            if (ln == 0) {
                int m = wm * 64 + mt * 16 + quad * 4 + r;
                red[m * 2 + wn] = part;
            }
        }
    }
    __syncthreads();
    if (t < 128) {
        float d2 = red[t * 2] + red[t * 2 + 1];
        out[(size_t)(b0 + t) * C_ + c] = expf(-0.5f * d2);
    }
}

extern "C" void kernel_launch(void* const* d_in, const int* in_sizes, int n_in,
                              void* d_out, int out_size, void* d_ws, size_t ws_size,
                              hipStream_t stream) {
    const float* x  = (const float*)d_in[0];
    const float* W  = (const float*)d_in[1];
    const float* b  = (const float*)d_in[2];
    const float* u  = (const float*)d_in[3];
    const float* cc = (const float*)d_in[4];
    float* out = (float*)d_out;

    // workspace layout (all 16B aligned)
    char* ws = (char*)d_ws;
    _Float16* Wh      = (_Float16*)ws;                                // 52,428,800 B
    _Float16* xh      = (_Float16*)(ws + (size_t)C_ * F_ * E_ * 2);   //  2,097,152 B
    float*    ychunks = (float*)(ws + (size_t)C_ * F_ * E_ * 2 + (size_t)B_ * E_ * 2); // 819,200 B

    k_gram<<<1632, 256, 0, stream>>>(W, Wh, x, xh, u, ychunks);

    dim3 grid(B_ / 128, C_);
    k_main<<<grid, 256, 0, stream>>>(xh, Wh, b, cc, u, ychunks, out);
}